// Round 3
// baseline (1816.516 us; speedup 1.0000x reference)
//
#include <hip/hip_runtime.h>

// LSTM (B=512, T=1024, I=64, H=128) + FC(128->256->1), all fp32.
// Persistent fused kernel: 256 blocks x 1024 threads, 1 block/CU, BCHUNK=2
// batch rows per block for the whole T loop (rows independent -> no grid sync).
//
// v4: v3 measured 3977 cy/step vs ~2000 cy of honest issue; the gap was the
// per-step serial structure (gate LDS round-trip + 2 barriers + 256-thread
// phase C at ~120cy LDS latency while 12/16 waves idle). Re-map so the gate
// reduction is lane-local: thread tid = 8*j + c owns the VERTICAL gate set
// {j, j+128, j+256, j+384} = (i,f,g~,o) of hidden unit j, over 24-col chunk
// c of z=[x|h]. After the 8-lane fold (xor4 row-select via ds_swizzle, then
// redundant symmetric xor2/xor1 via DPP — every lane ends with all 4 gate
// pre-acts of (j, row c>>2)), the c/h update runs entirely in registers
// (c-state 4-way redundant, bit-consistent) and lane (c&3)==0 writes h
// directly to the double-buffered zbuf. One barrier per step, no gbuf, no
// phase C. x(t+1) prefetch stores into the next buffer under the same
// barrier.

#define T_STEPS 1024
#define ISZ 64
#define HSZ 128
#define ZSZ (ISZ + HSZ)   // concat operand per row: [x_t | h_{t-1}]
#define BCHUNK 2
#define NTH 1024
#define CLEN 24           // K-chunk length per thread (192/8)
#define NGATE 4           // gate rows per thread (the 4 gates of hidden unit j)

__device__ __forceinline__ float fast_sigmoid(float x) {
    // 1/(1+e^-x): e^x overflow -> 1/(1+inf)=0, underflow -> 1. No NaN.
    return 1.0f / (1.0f + __expf(-x));
}

__device__ __forceinline__ float fast_tanh(float x) {
    // (e^2x - 1)/(e^2x + 1): exact near 0 (no cancellation), clamp avoids inf/inf.
    float xc = fminf(fmaxf(x, -15.0f), 15.0f);
    float u = __expf(2.0f * xc);
    return (u - 1.0f) / (u + 1.0f);
}

// DPP lane exchanges within quads (VALU pipe, no LDS traffic).
__device__ __forceinline__ float dpp_xor1(float v) {  // quad_perm [1,0,3,2]
    return __int_as_float(__builtin_amdgcn_mov_dpp(__float_as_int(v), 0xB1, 0xF, 0xF, true));
}
__device__ __forceinline__ float dpp_xor2(float v) {  // quad_perm [2,3,0,1]
    return __int_as_float(__builtin_amdgcn_mov_dpp(__float_as_int(v), 0x4E, 0xF, 0xF, true));
}
// lane ^= 4 via ds_swizzle BitMode: offset = (xor<<10)|(or<<5)|and = 0x101F
__device__ __forceinline__ float swz_xor4(float v) {
    return __int_as_float(__builtin_amdgcn_ds_swizzle(__float_as_int(v), 0x101F));
}

__global__ __launch_bounds__(NTH, 4)  // 16 waves/block = 4 waves/EU -> 128-reg combined budget
void lstm_fused_kernel(const float* __restrict__ x,
                       const float* __restrict__ W_ih,
                       const float* __restrict__ W_hh,
                       const float* __restrict__ b_ih,
                       const float* __restrict__ b_hh,
                       const float* __restrict__ W1,
                       const float* __restrict__ b1,
                       const float* __restrict__ W2,
                       const float* __restrict__ b2,
                       float* __restrict__ out)
{
    // double-buffered [x_t(64) | h(128)] per row; step t reads buf t&1,
    // writes h(t) and x(t+1) into buf (t&1)^1. One barrier per step.
    __shared__ __align__(16) float zbuf[2][BCHUNK][ZSZ];
    __shared__ float red[BCHUNK][4];

    const int tid = threadIdx.x;
    const int b0 = blockIdx.x * BCHUNK;
    const int c  = tid & 7;      // K-chunk index (0..7); bit2 = row after fold
    const int j  = tid >> 3;     // hidden unit 0..127
    const int myrow = c >> 2;    // row this lane owns after the xor4 stage
    const bool hi4 = (c & 4) != 0;

    // ---- per-thread weights: gate rows {j,j+128,j+256,j+384}, cols [24c,24c+24) ----
    // One-time load (L2/L3 cached); per-element address select is init-only cost.
    float wt[NGATE][CLEN];
    float bs[NGATE];
    #pragma unroll
    for (int i = 0; i < NGATE; ++i) {
        const int g = j + HSZ * i;          // i=0:input 1:forget 2:cell 3:output
        const float* rih = W_ih + (size_t)g * ISZ;
        const float* rhh = W_hh + (size_t)g * HSZ;
        #pragma unroll
        for (int k = 0; k < CLEN; ++k) {
            const int col = c * CLEN + k;
            wt[i][k] = (col < ISZ) ? rih[col] : rhh[col - ISZ];
        }
        bs[i] = b_ih[g] + b_hh[g];
    }

    // ---- init buf0: h(-1)=0, x(0) ----
    if (tid < BCHUNK * HSZ) zbuf[0][tid >> 7][ISZ + (tid & 127)] = 0.0f;
    if (tid >= 256 && tid < 256 + BCHUNK * ISZ) {
        int l = tid - 256;
        zbuf[0][l >> 6][l & 63] =
            x[((size_t)(b0 + (l >> 6)) * T_STEPS + 0) * ISZ + (l & 63)];
    }
    float cst = 0.0f;   // cell state of (j, myrow); 4-way redundant across c&3, bit-consistent
    __syncthreads();

    for (int t = 0; t < T_STEPS; ++t) {
        const int p = t & 1;
        const int q = p ^ 1;

        // issue x(t+1) prefetch early (threads 512..639); stored to zbuf[q] pre-barrier
        float xpre = 0.0f;
        const bool pf = (tid >= 512) && (tid < 640) && (t + 1 < T_STEPS);
        if (pf) {
            int l = tid - 512;
            xpre = x[((size_t)(b0 + (l >> 6)) * T_STEPS + (t + 1)) * ISZ + (l & 63)];
        }

        // ---- phase A: partial pre-activations over this thread's 24-col chunk ----
        float a[NGATE][BCHUNK];
        #pragma unroll
        for (int i = 0; i < NGATE; ++i) { a[i][0] = 0.0f; a[i][1] = 0.0f; }
        #pragma unroll
        for (int r = 0; r < BCHUNK; ++r) {
            const float4* zr = reinterpret_cast<const float4*>(zbuf[p][r]) + c * (CLEN / 4);
            #pragma unroll
            for (int k = 0; k < CLEN / 4; ++k) {
                float4 u = zr[k];
                #pragma unroll
                for (int i = 0; i < NGATE; ++i) {
                    a[i][r] = fmaf(wt[i][4*k  ], u.x, a[i][r]);
                    a[i][r] = fmaf(wt[i][4*k+1], u.y, a[i][r]);
                    a[i][r] = fmaf(wt[i][4*k+2], u.z, a[i][r]);
                    a[i][r] = fmaf(wt[i][4*k+3], u.w, a[i][r]);
                }
            }
        }

        // ---- fold across the 8 chunk lanes (partners share j) ----
        // xor4: row-select stage — lane keeps its row, receives partner's partial
        // xor2/xor1: symmetric redundant sums (no selects; all lanes get the total)
        float s0, s1, s2, s3;
        {
            float g0 = (hi4 ? a[0][1] : a[0][0]) + swz_xor4(hi4 ? a[0][0] : a[0][1]);
            float g1 = (hi4 ? a[1][1] : a[1][0]) + swz_xor4(hi4 ? a[1][0] : a[1][1]);
            float g2 = (hi4 ? a[2][1] : a[2][0]) + swz_xor4(hi4 ? a[2][0] : a[2][1]);
            float g3 = (hi4 ? a[3][1] : a[3][0]) + swz_xor4(hi4 ? a[3][0] : a[3][1]);
            g0 += dpp_xor2(g0); g1 += dpp_xor2(g1); g2 += dpp_xor2(g2); g3 += dpp_xor2(g3);
            s0 = g0 + dpp_xor1(g0) + bs[0];
            s1 = g1 + dpp_xor1(g1) + bs[1];
            s2 = g2 + dpp_xor1(g2) + bs[2];
            s3 = g3 + dpp_xor1(g3) + bs[3];
        }

        // ---- lane-local c/h update (4-way redundant across c&3; bit-consistent) ----
        float ig = fast_sigmoid(s0);
        float fg = fast_sigmoid(s1);
        float gv = fast_tanh(s2);
        float og = fast_sigmoid(s3);
        cst = fmaf(fg, cst, ig * gv);
        float hval = og * fast_tanh(cst);
        if ((c & 3) == 0) zbuf[q][myrow][ISZ + j] = hval;   // one writer per (j,row)

        // x(t+1) store into next buffer (disjoint region from h writes)
        if (pf) {
            int l = tid - 512;
            zbuf[q][l >> 6][l & 63] = xpre;
        }
        __syncthreads();   // buf q complete: h(t) + x(t+1)
    }

    // ---- FC head: out[b] = W2 . (W1 h + b1) + b2 (threads 0..511) ----
    // last step t=1023 wrote h into buf ((1023&1)^1) = 0
    if (tid < 512) {
        const int b = tid >> 8;    // threads 0..255 -> row b0, 256..511 -> row b0+1
        const int m = tid & 255;
        const float4* w1r = reinterpret_cast<const float4*>(W1 + (size_t)m * HSZ);
        const float4* hr = reinterpret_cast<const float4*>(zbuf[0][b] + ISZ);
        float acc = 0.0f;
        #pragma unroll
        for (int k = 0; k < HSZ / 4; ++k) {
            float4 w = w1r[k];
            float4 h = hr[k];
            acc = fmaf(w.x, h.x, acc);
            acc = fmaf(w.y, h.y, acc);
            acc = fmaf(w.z, h.z, acc);
            acc = fmaf(w.w, h.w, acc);
        }
        float z = (acc + b1[m]) * W2[m];
        #pragma unroll
        for (int off = 32; off >= 1; off >>= 1)
            z += __shfl_down(z, off, 64);
        if ((tid & 63) == 0) red[b][(tid >> 6) & 3] = z;
    }
    __syncthreads();
    if (tid == 0)   out[b0]     = red[0][0] + red[0][1] + red[0][2] + red[0][3] + b2[0];
    if (tid == 256) out[b0 + 1] = red[1][0] + red[1][1] + red[1][2] + red[1][3] + b2[0];
}

extern "C" void kernel_launch(void* const* d_in, const int* in_sizes, int n_in,
                              void* d_out, int out_size, void* d_ws, size_t ws_size,
                              hipStream_t stream) {
    const float* x    = (const float*)d_in[0];
    const float* W_ih = (const float*)d_in[1];
    const float* W_hh = (const float*)d_in[2];
    const float* b_ih = (const float*)d_in[3];
    const float* b_hh = (const float*)d_in[4];
    const float* W1   = (const float*)d_in[5];
    const float* b1   = (const float*)d_in[6];
    const float* W2   = (const float*)d_in[7];
    const float* b2   = (const float*)d_in[8];
    float* out = (float*)d_out;

    lstm_fused_kernel<<<dim3(512 / BCHUNK), dim3(NTH), 0, stream>>>(
        x, W_ih, W_hh, b_ih, b_hh, W1, b1, W2, b2, out);
}

// Round 4
// 1440.947 us; speedup vs baseline: 1.2606x; 1.2606x over previous
//
#include <hip/hip_runtime.h>

// LSTM (B=512, T=1024, I=64, H=128) + FC(128->256->1), all fp32.
// Persistent fused kernel: 256 blocks x 1024 threads, 1 block/CU, BCHUNK=2
// batch rows per block for the whole T loop (rows independent -> no grid sync).
//
// v5: v4 post-mortem showed the regression was transcendental issue cost
// (5 exp + 5 rcp per lane per step, quarter-rate ~16cy/wave each => +640
// cy/step vs v3). v5 keeps v4's single-barrier structure but does ONE
// activation per lane (v3-style distribution) with:
//  - thread tid = 8j + c owns the 4 gate classes {j, j+128, j+256, j+384}
//    of hidden unit j over 24-col chunk c of z=[x|h];
//  - all-DPP fold over the 8 chunk lanes using involution basis
//    {xor7=half_mirror, xor2, xor1} (7^2^1=4 spans xor4 -> no ds_swizzle,
//    no LDS-pipe fold traffic, no bank conflicts). After the fold lane c
//    owns pre-activation of (class=c&3, row=c>>2) for unit j;
//  - branchless fused activation: sigmoid = 0 + 1*rcp(e^{-s}+1),
//    tanh = 1 - 2*rcp(e^{2s}+1) -- same exp/rcp skeleton, per-lane consts,
//    inf-safe without clamps;
//  - quad-local c/h update: classes of (j,row) sit in one quad; a 2-stage
//    quad-DPP exchange gives all 4 lanes (ig*gv, fg) bit-consistently,
//    cst updates redundantly in-register, class-3 lane (holds og) writes h.
// One barrier per step, double-buffered z, no gbuf, 2 exp + 2 rcp per lane.

#define T_STEPS 1024
#define ISZ 64
#define HSZ 128
#define ZSZ (ISZ + HSZ)   // concat operand per row: [x_t | h_{t-1}]
#define BCHUNK 2
#define NTH 1024
#define CLEN 24           // K-chunk length per thread (192/8)
#define NGATE 4           // gate rows per thread (4 classes of unit j)

#define DPP_X1 0xB1       // quad_perm [1,0,3,2]  : lane ^= 1
#define DPP_X2 0x4E       // quad_perm [2,3,0,1]  : lane ^= 2
#define DPP_HM 0x141      // half_mirror          : lane ^= 7 (within 8-lane half)

template<int CTRL>
__device__ __forceinline__ float dppf(float v) {
    return __int_as_float(__builtin_amdgcn_mov_dpp(__float_as_int(v), CTRL, 0xF, 0xF, true));
}

__global__ __launch_bounds__(NTH, 4)  // 16 waves/block = 4 waves/EU -> 128-reg combined budget
void lstm_fused_kernel(const float* __restrict__ x,
                       const float* __restrict__ W_ih,
                       const float* __restrict__ W_hh,
                       const float* __restrict__ b_ih,
                       const float* __restrict__ b_hh,
                       const float* __restrict__ W1,
                       const float* __restrict__ b1,
                       const float* __restrict__ W2,
                       const float* __restrict__ b2,
                       float* __restrict__ out)
{
    // double-buffered [x_t(64) | h(128)] per row; step t reads one buffer,
    // writes h(t) and x(t+1) into the other. One barrier per step.
    __shared__ __align__(16) float zbuf[2][BCHUNK][ZSZ];
    __shared__ float red[BCHUNK][4];

    const int tid = threadIdx.x;
    const int b0 = blockIdx.x * BCHUNK;
    const int c  = tid & 7;      // chunk lane (0..7)
    const int j  = tid >> 3;     // hidden unit 0..127
    const int cls = c & 3;       // gate class this lane owns after fold
    const int row = c >> 2;      // batch row this lane owns after fold

    // basis coordinates of lane c in {7,2,1}: c = alpha*7 ^ beta*2 ^ gamma*1
    const bool alpha = (c & 4) != 0;
    const int  c1r = c ^ (alpha ? 7 : 0);
    const bool beta  = (c1r & 2) != 0;
    const bool gamma = ((c1r ^ (beta ? 2 : 0)) & 1) != 0;
    const bool cls3  = (cls == 3);
    const bool cls13 = (cls & 1) != 0;

    // fused-activation constants: act = aa + bb * rcp(exp(kk*s) + 1)
    // cls 0,1,3 (sigmoid): kk=-1, aa=0, bb=1 ; cls 2 (tanh): kk=2, aa=1, bb=-2
    const float kk = (cls == 2) ?  2.0f : -1.0f;
    const float aa = (cls == 2) ?  1.0f :  0.0f;
    const float bb = (cls == 2) ? -2.0f :  1.0f;

    // ---- per-thread weights: gate rows {j,j+128,j+256,j+384}, cols [24c,24c+24) ----
    float wt[NGATE][CLEN];
    #pragma unroll
    for (int i = 0; i < NGATE; ++i) {
        const float* rih = W_ih + (size_t)(j + HSZ * i) * ISZ;
        const float* rhh = W_hh + (size_t)(j + HSZ * i) * HSZ;
        #pragma unroll
        for (int k = 0; k < CLEN; ++k) {
            const int col = c * CLEN + k;
            wt[i][k] = (col < ISZ) ? rih[col] : rhh[col - ISZ];
        }
    }
    const int g_own = cls * HSZ + j;
    const float bias = b_ih[g_own] + b_hh[g_own];

    // ---- init buf0: h(-1)=0, x(0) ----
    if (tid < BCHUNK * HSZ) zbuf[0][tid >> 7][ISZ + (tid & 127)] = 0.0f;
    if (tid >= 256 && tid < 256 + BCHUNK * ISZ) {
        int l = tid - 256;
        zbuf[0][l >> 6][l & 63] =
            x[((size_t)(b0 + (l >> 6)) * T_STEPS + 0) * ISZ + (l & 63)];
    }
    float cst = 0.0f;   // cell state of (j,row); 4-way redundant across the quad, bit-consistent
    __syncthreads();

    auto step = [&](const float (*__restrict__ zr)[ZSZ],
                    float (*__restrict__ zw)[ZSZ], int t) {
        // x(t+1) prefetch issue (threads 512..639), stored to zw pre-barrier
        float xpre = 0.0f;
        const bool pf = (tid >= 512) && (tid < 640) && (t + 1 < T_STEPS);
        if (pf) {
            int l = tid - 512;
            xpre = x[((size_t)(b0 + (l >> 6)) * T_STEPS + (t + 1)) * ISZ + (l & 63)];
        }

        // ---- phase A: chunk partials for 4 classes x 2 rows ----
        float a[NGATE][BCHUNK];
        #pragma unroll
        for (int i = 0; i < NGATE; ++i) { a[i][0] = 0.0f; a[i][1] = 0.0f; }
        #pragma unroll
        for (int r = 0; r < BCHUNK; ++r) {
            const float4* zp = reinterpret_cast<const float4*>(zr[r]) + c * (CLEN / 4);
            #pragma unroll
            for (int k = 0; k < CLEN / 4; ++k) {
                float4 u = zp[k];
                #pragma unroll
                for (int i = 0; i < NGATE; ++i) {
                    a[i][r] = fmaf(wt[i][4*k  ], u.x, a[i][r]);
                    a[i][r] = fmaf(wt[i][4*k+1], u.y, a[i][r]);
                    a[i][r] = fmaf(wt[i][4*k+2], u.z, a[i][r]);
                    a[i][r] = fmaf(wt[i][4*k+3], u.w, a[i][r]);
                }
            }
        }

        // ---- all-DPP fold over 8 lanes, basis {7,2,1}; lane c ends with
        //      (class=c&3, row=c>>2). Value->coord table (target lane 4r+cl):
        float A000 = a[0][0], A001 = a[1][0], A010 = a[2][0], A011 = a[3][0];
        float A100 = a[3][1], A101 = a[2][1], A110 = a[1][1], A111 = a[0][1];
        float B00 = (alpha ? A100 : A000) + dppf<DPP_HM>(alpha ? A000 : A100);
        float B01 = (alpha ? A101 : A001) + dppf<DPP_HM>(alpha ? A001 : A101);
        float B10 = (alpha ? A110 : A010) + dppf<DPP_HM>(alpha ? A010 : A110);
        float B11 = (alpha ? A111 : A011) + dppf<DPP_HM>(alpha ? A011 : A111);
        float C0  = (beta ? B10 : B00) + dppf<DPP_X2>(beta ? B00 : B10);
        float C1  = (beta ? B11 : B01) + dppf<DPP_X2>(beta ? B01 : B11);
        float S   = (gamma ? C1 : C0) + dppf<DPP_X1>(gamma ? C0 : C1);
        S += bias;

        // ---- fused activation (branchless; inf-safe, no clamps) ----
        float e   = __expf(kk * S);
        float act = fmaf(bb, __builtin_amdgcn_rcpf(e + 1.0f), aa);

        // ---- quad-local c/h update ----
        // xor2 partner: class^2 (0<->2 ig/gv, 1<->3 fg/og)
        float prt = dppf<DPP_X2>(act);
        float m1  = act * prt;                 // classes 0,2: ig*gv (bitwise equal)
        float fgv = cls3 ? prt : act;          // classes 1,3: fg
        float x1v = cls13 ? fgv : m1;
        float rcv = dppf<DPP_X1>(x1v);         // swap with class^1
        float m1v = cls13 ? rcv : x1v;         // everyone: ig*gv
        float fgf = cls13 ? x1v : rcv;         // everyone: fg
        cst = fmaf(fgf, cst, m1v);
        float e2 = __expf(2.0f * cst);
        float th = fmaf(-2.0f, __builtin_amdgcn_rcpf(e2 + 1.0f), 1.0f);  // tanh(cst)
        if (cls3) zw[row][ISZ + j] = act * th; // act = og on class-3 lane

        // x(t+1) store into next buffer (disjoint region from h writes)
        if (pf) {
            int l = tid - 512;
            zw[l >> 6][l & 63] = xpre;
        }
        __syncthreads();   // zw complete: h(t) + x(t+1)
    };

    for (int t = 0; t < T_STEPS; t += 2) {
        step(zbuf[0], zbuf[1], t);
        step(zbuf[1], zbuf[0], t + 1);
    }

    // ---- FC head: out[b] = W2 . (W1 h + b1) + b2 (threads 0..511) ----
    // last step t=1023 wrote h into zbuf[0]
    if (tid < 512) {
        const int b = tid >> 8;    // threads 0..255 -> row b0, 256..511 -> row b0+1
        const int m = tid & 255;
        const float4* w1r = reinterpret_cast<const float4*>(W1 + (size_t)m * HSZ);
        const float4* hr = reinterpret_cast<const float4*>(zbuf[0][b] + ISZ);
        float acc = 0.0f;
        #pragma unroll
        for (int k = 0; k < HSZ / 4; ++k) {
            float4 w = w1r[k];
            float4 h = hr[k];
            acc = fmaf(w.x, h.x, acc);
            acc = fmaf(w.y, h.y, acc);
            acc = fmaf(w.z, h.z, acc);
            acc = fmaf(w.w, h.w, acc);
        }
        float z = (acc + b1[m]) * W2[m];
        #pragma unroll
        for (int off = 32; off >= 1; off >>= 1)
            z += __shfl_down(z, off, 64);
        if ((tid & 63) == 0) red[b][(tid >> 6) & 3] = z;
    }
    __syncthreads();
    if (tid == 0)   out[b0]     = red[0][0] + red[0][1] + red[0][2] + red[0][3] + b2[0];
    if (tid == 256) out[b0 + 1] = red[1][0] + red[1][1] + red[1][2] + red[1][3] + b2[0];
}

extern "C" void kernel_launch(void* const* d_in, const int* in_sizes, int n_in,
                              void* d_out, int out_size, void* d_ws, size_t ws_size,
                              hipStream_t stream) {
    const float* x    = (const float*)d_in[0];
    const float* W_ih = (const float*)d_in[1];
    const float* W_hh = (const float*)d_in[2];
    const float* b_ih = (const float*)d_in[3];
    const float* b_hh = (const float*)d_in[4];
    const float* W1   = (const float*)d_in[5];
    const float* b1   = (const float*)d_in[6];
    const float* W2   = (const float*)d_in[7];
    const float* b2   = (const float*)d_in[8];
    float* out = (float*)d_out;

    lstm_fused_kernel<<<dim3(512 / BCHUNK), dim3(NTH), 0, stream>>>(
        x, W_ih, W_hh, b_ih, b_hh, W1, b1, W2, b2, out);
}